// Round 5
// baseline (99.516 us; speedup 1.0000x reference)
//
#include <hip/hip_runtime.h>
#include <math.h>

#define BB 64
#define SS 1024
#define DD 1024
#define HH 128
#define KK 8
#define EPS 1e-6f

// Native clang vector type: __builtin_nontemporal_load/store require a
// pointer to a true vector type (HIP's float4 is a struct and is rejected).
typedef float vfloat4 __attribute__((ext_vector_type(4)));

// ---------------- Router: prob[B,K] + idx[B] ----------------
// One block per batch element, 1024 threads (16 waves).
// D-reduction split 8 ways: thread t handles hidden unit (t&127),
// partial sum over D-slice (t>>7)*128..+128. Serial depth 128.
__global__ __launch_bounds__(1024) void router_kernel(
    const float* __restrict__ x, const float* __restrict__ w1,
    const float* __restrict__ b1, const float* __restrict__ w2,
    const float* __restrict__ b2, float* __restrict__ prob_out,
    int* __restrict__ idx_out)
{
    __shared__ float cls[DD];
    __shared__ float partial[8][HH];
    __shared__ float h[HH];
    __shared__ float logits[KK];
    const int b = blockIdx.x;
    const int t = threadIdx.x;

    // Load CLS token (x[b, 0, :]) as float4 (256 lanes needed).
    const float* xrow = x + (size_t)b * SS * DD;
    if (t < DD / 4) ((vfloat4*)cls)[t] = ((const vfloat4*)xrow)[t];
    __syncthreads();

    // Partial GEMV: w1 is [D, H] row-major -> lanes read consecutive floats.
    const int hh = t & (HH - 1);
    const int part = t >> 7;                 // 0..7
    const float* w1p = w1 + (size_t)(part * 128) * HH + hh;
    const float* cp = cls + part * 128;
    float acc = 0.f;
    #pragma unroll 8
    for (int d = 0; d < 128; ++d) acc += cp[d] * w1p[d * HH];
    partial[part][hh] = acc;
    __syncthreads();

    if (t < HH) {
        float a = b1[t];
        #pragma unroll
        for (int p = 0; p < 8; ++p) a += partial[p][t];
        // exact GELU: 0.5*x*(1+erf(x/sqrt(2)))
        h[t] = 0.5f * a * (1.0f + erff(a * 0.70710678118654752f));
    }
    __syncthreads();

    // logits: one wave; 8 lanes per k, each sums 16 h-values, xor-reduce.
    if (t < 64) {
        const int k = t >> 3;
        const int j0 = (t & 7) * 16;
        float l = 0.f;
        #pragma unroll
        for (int j = 0; j < 16; ++j) l += h[j0 + j] * w2[(j0 + j) * KK + k];
        l += __shfl_xor(l, 1);
        l += __shfl_xor(l, 2);
        l += __shfl_xor(l, 4);
        if ((t & 7) == 0) logits[k] = l + b2[k];
    }
    __syncthreads();

    if (t == 0) {
        float m = logits[0];
        #pragma unroll
        for (int k = 1; k < KK; ++k) m = fmaxf(m, logits[k]);
        float e[KK], s = 0.f;
        #pragma unroll
        for (int k = 0; k < KK; ++k) { e[k] = expf(logits[k] - m); s += e[k]; }
        const float inv = 1.0f / s;
        int best = 0; float bv = logits[0];
        #pragma unroll
        for (int k = 1; k < KK; ++k) if (logits[k] > bv) { bv = logits[k]; best = k; }
        #pragma unroll
        for (int k = 0; k < KK; ++k) prob_out[b * KK + k] = e[k] * inv;
        idx_out[b] = best;
    }
}

// ---------------- LayerNorm bank: one wave per TWO rows ----------------
// 8 NT float4 loads issued back-to-back per lane (128 B in flight), two
// independent reduce chains (ILP through the butterfly), shared idx/g/b
// (both rows are in the same batch since 2 | S), two apply+store passes.
__global__ __launch_bounds__(256) void ln_kernel(
    const float* __restrict__ x, const float* __restrict__ gammas,
    const float* __restrict__ betas, const int* __restrict__ idx,
    float* __restrict__ out)
{
    const int wave = threadIdx.x >> 6;
    const int lane = threadIdx.x & 63;
    const size_t row0 = ((size_t)blockIdx.x * 4 + wave) * 2;  // rows [row0, row0+1]
    const int b = (int)(row0 >> 10);                          // S = 1024

    const vfloat4* xr0 = (const vfloat4*)(x + row0 * DD);
    const vfloat4* xr1 = (const vfloat4*)(x + (row0 + 1) * DD);
    vfloat4 v0[4], v1[4];
    // Issue all 8 loads before any arithmetic: maximize outstanding VMEM.
    #pragma unroll
    for (int i = 0; i < 4; ++i) v0[i] = __builtin_nontemporal_load(xr0 + i * 64 + lane);
    #pragma unroll
    for (int i = 0; i < 4; ++i) v1[i] = __builtin_nontemporal_load(xr1 + i * 64 + lane);

    float sum0 = 0.f, sq0 = 0.f, sum1 = 0.f, sq1 = 0.f;
    #pragma unroll
    for (int i = 0; i < 4; ++i) {
        sum0 += v0[i].x + v0[i].y + v0[i].z + v0[i].w;
        sq0  += v0[i].x * v0[i].x + v0[i].y * v0[i].y + v0[i].z * v0[i].z + v0[i].w * v0[i].w;
        sum1 += v1[i].x + v1[i].y + v1[i].z + v1[i].w;
        sq1  += v1[i].x * v1[i].x + v1[i].y * v1[i].y + v1[i].z * v1[i].z + v1[i].w * v1[i].w;
    }
    // wave-wide butterfly reduce (64 lanes), 4 interleaved chains
    #pragma unroll
    for (int off = 32; off > 0; off >>= 1) {
        sum0 += __shfl_xor(sum0, off);
        sq0  += __shfl_xor(sq0, off);
        sum1 += __shfl_xor(sum1, off);
        sq1  += __shfl_xor(sq1, off);
    }
    const float mean0 = sum0 * (1.0f / DD);
    const float rstd0 = rsqrtf(sq0 * (1.0f / DD) - mean0 * mean0 + EPS);
    const float mean1 = sum1 * (1.0f / DD);
    const float rstd1 = rsqrtf(sq1 * (1.0f / DD) - mean1 * mean1 + EPS);

    const int e = idx[b];
    const vfloat4* gr = (const vfloat4*)(gammas + (size_t)e * DD);
    const vfloat4* br = (const vfloat4*)(betas  + (size_t)e * DD);
    vfloat4* orow0 = (vfloat4*)(out + row0 * DD);
    vfloat4* orow1 = (vfloat4*)(out + (row0 + 1) * DD);
    #pragma unroll
    for (int i = 0; i < 4; ++i) {
        const vfloat4 g  = gr[i * 64 + lane];
        const vfloat4 bt = br[i * 64 + lane];
        vfloat4 o0, o1;
        o0.x = (v0[i].x - mean0) * rstd0 * g.x + bt.x;
        o0.y = (v0[i].y - mean0) * rstd0 * g.y + bt.y;
        o0.z = (v0[i].z - mean0) * rstd0 * g.z + bt.z;
        o0.w = (v0[i].w - mean0) * rstd0 * g.w + bt.w;
        o1.x = (v1[i].x - mean1) * rstd1 * g.x + bt.x;
        o1.y = (v1[i].y - mean1) * rstd1 * g.y + bt.y;
        o1.z = (v1[i].z - mean1) * rstd1 * g.z + bt.z;
        o1.w = (v1[i].w - mean1) * rstd1 * g.w + bt.w;
        __builtin_nontemporal_store(o0, orow0 + i * 64 + lane);
        __builtin_nontemporal_store(o1, orow1 + i * 64 + lane);
    }
}

extern "C" void kernel_launch(void* const* d_in, const int* in_sizes, int n_in,
                              void* d_out, int out_size, void* d_ws, size_t ws_size,
                              hipStream_t stream) {
    const float* x      = (const float*)d_in[0];
    const float* gammas = (const float*)d_in[1];
    const float* betas  = (const float*)d_in[2];
    const float* w1     = (const float*)d_in[3];
    const float* b1     = (const float*)d_in[4];
    const float* w2     = (const float*)d_in[5];
    const float* b2     = (const float*)d_in[6];

    float* out  = (float*)d_out;                       // [B,S,D] flat
    float* prob = out + (size_t)BB * SS * DD;          // [B,K] appended
    int*   idx  = (int*)d_ws;                          // scratch: B ints

    router_kernel<<<BB, 1024, 0, stream>>>(x, w1, b1, w2, b2, prob, idx);

    const int rows_per_block = 8;                      // 4 waves x 2 rows
    const int nblocks = (BB * SS) / rows_per_block;    // 8192
    ln_kernel<<<nblocks, 256, 0, stream>>>(x, gammas, betas, idx, out);
}

// Round 6
// 97.504 us; speedup vs baseline: 1.0206x; 1.0206x over previous
//
#include <hip/hip_runtime.h>
#include <math.h>

#define BB 64
#define SS 1024
#define DD 1024
#define HH 128
#define KK 8
#define EPS 1e-6f

// Native clang vector type: __builtin_nontemporal_load/store require a
// pointer to a true vector type (HIP's float4 is a struct and is rejected).
typedef float vfloat4 __attribute__((ext_vector_type(4)));

// ---------------- Router: prob[B,K] + idx[B] ----------------
// One block per batch element, 1024 threads (16 waves).
// D-reduction split 8 ways: thread t handles hidden unit (t&127),
// partial sum over D-slice (t>>7)*128..+128. Serial depth 128, unroll 32
// (32 loads in flight -> 4 dependent load batches instead of 16).
__global__ __launch_bounds__(1024) void router_kernel(
    const float* __restrict__ x, const float* __restrict__ w1,
    const float* __restrict__ b1, const float* __restrict__ w2,
    const float* __restrict__ b2, float* __restrict__ prob_out,
    int* __restrict__ idx_out)
{
    __shared__ float cls[DD];
    __shared__ float partial[8][HH];
    __shared__ float h[HH];
    const int b = blockIdx.x;
    const int t = threadIdx.x;

    // Load CLS token (x[b, 0, :]) as float4 (256 lanes needed).
    const float* xrow = x + (size_t)b * SS * DD;
    if (t < DD / 4) ((vfloat4*)cls)[t] = ((const vfloat4*)xrow)[t];
    __syncthreads();

    // Partial GEMV: w1 is [D, H] row-major -> lanes read consecutive floats.
    const int hh = t & (HH - 1);
    const int part = t >> 7;                 // 0..7
    const float* w1p = w1 + (size_t)(part * 128) * HH + hh;
    const float* cp = cls + part * 128;
    float acc = 0.f;
    #pragma unroll 32
    for (int d = 0; d < 128; ++d) acc += cp[d] * w1p[d * HH];
    partial[part][hh] = acc;
    __syncthreads();

    if (t < HH) {
        float a = b1[t];
        #pragma unroll
        for (int p = 0; p < 8; ++p) a += partial[p][t];
        // exact GELU: 0.5*x*(1+erf(x/sqrt(2)))
        h[t] = 0.5f * a * (1.0f + erff(a * 0.70710678118654752f));
    }
    __syncthreads();

    // logits + softmax + argmax, all inside wave 0 (no further barriers).
    if (t < 64) {
        const int k = t >> 3;                 // 0..7
        const int j0 = (t & 7) * 16;
        float l = 0.f;
        #pragma unroll
        for (int j = 0; j < 16; ++j) l += h[j0 + j] * w2[(j0 + j) * KK + k];
        l += __shfl_xor(l, 1);
        l += __shfl_xor(l, 2);
        l += __shfl_xor(l, 4);
        l += b2[k];                           // lanes 8k..8k+7 all hold logits[k]
        // lane t<8 gathers logit k=t via cross-lane read (lane 8k holds it)
        const float lk = __shfl(l, (t & 7) * 8);  // lane t: logits[t&7]
        if (t < 8) {
            // all of lanes 0..7 now hold logits[0..7] via lk
            float m = lk;
            #pragma unroll
            for (int off = 4; off > 0; off >>= 1) m = fmaxf(m, __shfl_xor(m, off));
            const float e = expf(lk - m);
            float s = e;
            #pragma unroll
            for (int off = 4; off > 0; off >>= 1) s += __shfl_xor(s, off);
            prob_out[b * KK + t] = e / s;
            if (t == 0) {
                int best = 0; float bv = lk;
                #pragma unroll
                for (int k2 = 1; k2 < KK; ++k2) {
                    const float v = __shfl(lk, k2);
                    if (v > bv) { bv = v; best = k2; }
                }
                idx_out[b] = best;
            }
        }
    }
}

// ---------------- LayerNorm bank: one wave (64 lanes) per row ----------------
// Round-4 configuration (measured 98.6 us total): 16 floats/lane in registers,
// single pass, NT loads/stores bypass L2 (gamma/beta keep the cache).
__global__ __launch_bounds__(256) void ln_kernel(
    const float* __restrict__ x, const float* __restrict__ gammas,
    const float* __restrict__ betas, const int* __restrict__ idx,
    float* __restrict__ out)
{
    const int wave = threadIdx.x >> 6;
    const int lane = threadIdx.x & 63;
    const size_t row = (size_t)blockIdx.x * 4 + wave;   // row in [0, B*S)
    const int b = (int)(row >> 10);                      // S = 1024

    const vfloat4* xr = (const vfloat4*)(x + row * DD);
    vfloat4 v[4];
    float sum = 0.f, sq = 0.f;
    #pragma unroll
    for (int i = 0; i < 4; ++i) {
        v[i] = __builtin_nontemporal_load(xr + i * 64 + lane);
        sum += v[i].x + v[i].y + v[i].z + v[i].w;
        sq  += v[i].x * v[i].x + v[i].y * v[i].y + v[i].z * v[i].z + v[i].w * v[i].w;
    }
    // wave-wide butterfly reduce (64 lanes)
    #pragma unroll
    for (int off = 32; off > 0; off >>= 1) {
        sum += __shfl_xor(sum, off);
        sq  += __shfl_xor(sq, off);
    }
    const float mean = sum * (1.0f / DD);
    const float var  = sq * (1.0f / DD) - mean * mean;   // biased (torch LN)
    const float rstd = rsqrtf(var + EPS);

    const int e = idx[b];
    const vfloat4* gr = (const vfloat4*)(gammas + (size_t)e * DD);
    const vfloat4* br = (const vfloat4*)(betas  + (size_t)e * DD);
    vfloat4* orow = (vfloat4*)(out + row * DD);
    #pragma unroll
    for (int i = 0; i < 4; ++i) {
        const vfloat4 g  = gr[i * 64 + lane];
        const vfloat4 bt = br[i * 64 + lane];
        vfloat4 o;
        o.x = (v[i].x - mean) * rstd * g.x + bt.x;
        o.y = (v[i].y - mean) * rstd * g.y + bt.y;
        o.z = (v[i].z - mean) * rstd * g.z + bt.z;
        o.w = (v[i].w - mean) * rstd * g.w + bt.w;
        __builtin_nontemporal_store(o, orow + i * 64 + lane);
    }
}

extern "C" void kernel_launch(void* const* d_in, const int* in_sizes, int n_in,
                              void* d_out, int out_size, void* d_ws, size_t ws_size,
                              hipStream_t stream) {
    const float* x      = (const float*)d_in[0];
    const float* gammas = (const float*)d_in[1];
    const float* betas  = (const float*)d_in[2];
    const float* w1     = (const float*)d_in[3];
    const float* b1     = (const float*)d_in[4];
    const float* w2     = (const float*)d_in[5];
    const float* b2     = (const float*)d_in[6];

    float* out  = (float*)d_out;                       // [B,S,D] flat
    float* prob = out + (size_t)BB * SS * DD;          // [B,K] appended
    int*   idx  = (int*)d_ws;                          // scratch: B ints

    router_kernel<<<BB, 1024, 0, stream>>>(x, w1, b1, w2, b2, prob, idx);

    const int rows_per_block = 4;                      // 256 threads = 4 waves
    const int nblocks = (BB * SS) / rows_per_block;    // 16384
    ln_kernel<<<nblocks, 256, 0, stream>>>(x, gammas, betas, idx, out);
}